// Round 7
// baseline (1512.460 us; speedup 1.0000x reference)
//
#include <hip/hip_runtime.h>
#include <math.h>

#define RESN  160
#define VOX   4096000          // 160^3
#define YSTR  160
#define ZSTR  25600            // 160*160
#define NPTS  478              // last sample index
#define NRAYS 2048
#define REC   32               // ushorts per voxel record = 64B

typedef float f2_u __attribute__((ext_vector_type(2), aligned(4)));

// ====================== transpose (reps for diagnostics) ======================
__global__ __launch_bounds__(256)
void diag_transpose(const float* __restrict__ sig, const float* __restrict__ rgb,
                    unsigned short* __restrict__ rec, const int* __restrict__ zi,
                    int reps)
{
    for (int rep = 0; rep < reps; ++rep) {
        const int v = blockIdx.x * 256 + threadIdx.x + zi[rep];   // zi[rep]==0 at runtime
        if ((unsigned)v >= VOX) continue;
        float vals[32];
        vals[0] = sig[v];
        #pragma unroll
        for (int k = 0; k < 27; ++k) vals[1 + k] = rgb[(size_t)k * VOX + v];
        vals[28] = vals[29] = vals[30] = vals[31] = 0.f;
        unsigned short hh[32];
        #pragma unroll
        for (int k = 0; k < 32; ++k) {
            unsigned u = __float_as_uint(vals[k]);
            unsigned r = (u + 0x7FFFu + ((u >> 16) & 1u)) >> 16;   // RNE to bf16
            hh[k] = (unsigned short)r;
        }
        uint4* dst = (uint4*)(rec + (size_t)v * REC);
        const uint4* src = (const uint4*)hh;
        #pragma unroll
        for (int i = 0; i < 4; ++i) dst[i] = src[i];
    }
}

__device__ __forceinline__ void bf2(unsigned u, float& lo, float& hi) {
    lo = __uint_as_float(u << 16);
    hi = __uint_as_float(u & 0xFFFF0000u);
}

#define ROUTE(slot, val)                                              \
    do {                                                              \
        if ((slot) == 0) sv += (val);                                 \
        else if ((slot) < 28) {                                       \
            const int _j = (slot) - 1;                                \
            const float _c = shv[_j % 9] * (val);                     \
            if (_j < 9) a0 += _c;                                     \
            else if (_j < 18) a1 += _c;                               \
            else a2 += _c;                                            \
        }                                                             \
    } while (0)

// ====================== record-based render (reps) ======================
__global__ __launch_bounds__(128)
void diag_render_rec(const float* __restrict__ rays_o,
                     const float* __restrict__ rays_d,
                     const unsigned short* __restrict__ rec,
                     float* __restrict__ out,
                     const float* __restrict__ zf, int reps)
{
    const int ray  = blockIdx.x;
    const int tid  = threadIdx.x;
    const int wave = tid >> 6;
    const int lane = tid & 63;

    const float ox = rays_o[ray*3+0], oy = rays_o[ray*3+1], oz = rays_o[ray*3+2];
    const float dxr = rays_d[ray*3+0], dyr = rays_d[ray*3+1], dzr = rays_d[ray*3+2];
    const float h = 2.6f * 1.7320508075688772f / 480.0f;

    const float dsq  = dxr*dxr + dyr*dyr + dzr*dzr;
    const float dinv = rsqrtf(dsq);
    const float dn   = sqrtf(dsq);
    const float X = dxr * dinv, Y = dyr * dinv, Z = dzr * dinv;
    const float shv[9] = {
        0.28209479177387814f, -0.4886025119029199f * Y, 0.4886025119029199f * Z,
        -0.4886025119029199f * X, 1.0925484305920792f * X * Y, -1.0925484305920792f * Y * Z,
        0.31539156525252005f * (2.0f * Z * Z - X * X - Y * Y),
        -1.0925484305920792f * X * Z, 0.5462742152960396f * (X * X - Y * Y),
    };
    const float dist = h * dn;

    __shared__ float sP[2], sR[2], sG[2], sB[2], sL[2];

    for (int rep = 0; rep < reps; ++rep) {
        const float oxj = ox + zf[rep];              // runtime zero — defeats LICM

        const float ax = (1.3f - oxj) / dxr, bx = (-1.3f - oxj) / dxr;
        const float ay = (1.3f - oy) / dyr,  by = (-1.3f - oy) / dyr;
        const float az = (1.3f - oz) / dzr,  bz = (-1.3f - oz) / dzr;
        float start = fmaxf(fmaxf(fminf(ax, bx), fminf(ay, by)), fminf(az, bz));
        start = fminf(fmaxf(start, 0.2f), 6.0f);

        const float B = 1.3164f;
        const float mx1 = ( B - oxj) / dxr, mx0 = (-B - oxj) / dxr;
        const float my1 = ( B - oy) / dyr,  my0 = (-B - oy) / dyr;
        const float mz1 = ( B - oz) / dzr,  mz0 = (-B - oz) / dzr;
        float tl = fmaxf(fmaxf(fminf(mx0, mx1), fminf(my0, my1)), fminf(mz0, mz1));
        float th = fminf(fminf(fmaxf(mx0, mx1), fmaxf(my0, my1)), fmaxf(mz0, mz1));
        tl = fmaxf(tl, start);
        th = fminf(th, fmaf((float)NPTS, h, start));
        int s_lo, s_hi;
        if (th < tl) { s_lo = 0; s_hi = -1; }
        else {
            s_lo = max(0,    (int)floorf((tl - start) / h) - 1);
            s_hi = min(NPTS, (int)ceilf ((th - start) / h) + 1);
        }

        float accR = 0.f, accG = 0.f, accB = 0.f, accL = 0.f;
        float carry = 1.0f;

        const int nlive = s_hi - s_lo + 1;
        if (nlive > 0) {
            const int chunk = (nlive + 1) >> 1;
            const int my_lo = s_lo + wave * chunk;
            const int my_hi = min(my_lo + chunk - 1, s_hi);

            for (int basei = my_lo; basei <= my_hi; basei += 64) {
                const int s = basei + lane;
                float alpha = 0.f, cr = 0.f, cg = 0.f, cb = 0.f;
                if (s <= my_hi) {
                    const float t  = fmaf((float)s, h, start);
                    const float px = fmaf(dxr, t, oxj);
                    const float py = fmaf(dyr, t, oy);
                    const float pz = fmaf(dzr, t, oz);
                    const float fx = fmaf(px, 61.153846153846f, 79.5f);
                    const float fy = fmaf(py, 61.153846153846f, 79.5f);
                    const float fz = fmaf(pz, 61.153846153846f, 79.5f);
                    const float fxf = floorf(fx), fyf = floorf(fy), fzf = floorf(fz);
                    const int   x0 = (int)fxf, y0 = (int)fyf, z0 = (int)fzf;
                    const float wx1 = fx - fxf, wy1 = fy - fyf, wz1 = fz - fzf;
                    const float wx0 = 1.f - wx1, wy0 = 1.f - wy1, wz0 = 1.f - wz1;

                    float sv = 0.f, a0 = 0.f, a1 = 0.f, a2 = 0.f;

                    if (x0 >= 0 && x0 <= 158 && y0 >= 0 && y0 <= 158 && z0 >= 0 && z0 <= 158) {
                        const float wzy[4] = { wz0*wy0, wz0*wy1, wz1*wy0, wz1*wy1 };
                        const size_t base = ((size_t)z0 * ZSTR + (size_t)y0 * YSTR + x0) * REC;
                        const uint4* P0 = (const uint4*)(rec + base);
                        const uint4* P1 = (const uint4*)(rec + base + (size_t)YSTR*REC);
                        const uint4* P2 = (const uint4*)(rec + base + (size_t)ZSTR*REC);
                        const uint4* P3 = (const uint4*)(rec + base + (size_t)(ZSTR+YSTR)*REC);
                        const uint4* PP[4] = { P0, P1, P2, P3 };
                        #pragma unroll
                        for (int half = 0; half < 2; ++half) {
                            uint4 r0[4][2], r1[4][2];
                            #pragma unroll
                            for (int p = 0; p < 4; ++p) {
                                r0[p][0] = PP[p][half*2+0]; r0[p][1] = PP[p][half*2+1];
                                r1[p][0] = PP[p][half*2+4]; r1[p][1] = PP[p][half*2+5];
                            }
                            #pragma unroll
                            for (int p = 0; p < 4; ++p) {
                                const float wA = wzy[p] * wx0, wB = wzy[p] * wx1;
                                #pragma unroll
                                for (int q = 0; q < 2; ++q) {
                                    const unsigned* u0 = (const unsigned*)&r0[p][q];
                                    const unsigned* u1 = (const unsigned*)&r1[p][q];
                                    #pragma unroll
                                    for (int d = 0; d < 4; ++d) {
                                        const int slot = half*16 + q*8 + d*2;
                                        if (slot >= 28) break;
                                        float l0, h0, l1, h1;
                                        bf2(u0[d], l0, h0);
                                        bf2(u1[d], l1, h1);
                                        const float vA  = fmaf(l1, wB, l0 * wA);
                                        const float vB2 = fmaf(h1, wB, h0 * wA);
                                        ROUTE(slot, vA);
                                        ROUTE(slot + 1, vB2);
                                    }
                                }
                            }
                        }
                    } else {
                        const float vwx[2] = { (x0   >= 0 && x0   < RESN) ? wx0 : 0.f,
                                               (x0+1 >= 0 && x0+1 < RESN) ? wx1 : 0.f };
                        const float vwy[2] = { (y0   >= 0 && y0   < RESN) ? wy0 : 0.f,
                                               (y0+1 >= 0 && y0+1 < RESN) ? wy1 : 0.f };
                        const float vwz[2] = { (z0   >= 0 && z0   < RESN) ? wz0 : 0.f,
                                               (z0+1 >= 0 && z0+1 < RESN) ? wz1 : 0.f };
                        const int cx[2] = { min(max(x0,0),RESN-1), min(max(x0+1,0),RESN-1) };
                        const int cy[2] = { min(max(y0,0),RESN-1), min(max(y0+1,0),RESN-1) };
                        const int cz[2] = { min(max(z0,0),RESN-1), min(max(z0+1,0),RESN-1) };
                        for (int dz = 0; dz < 2; ++dz)
                        for (int dy = 0; dy < 2; ++dy)
                        for (int dx = 0; dx < 2; ++dx) {
                            const float w = vwz[dz]*vwy[dy]*vwx[dx];
                            if (w == 0.f) continue;
                            const uint4* P = (const uint4*)(rec +
                                ((size_t)cz[dz]*ZSTR + (size_t)cy[dy]*YSTR + cx[dx]) * REC);
                            uint4 qq[4]; qq[0]=P[0]; qq[1]=P[1]; qq[2]=P[2]; qq[3]=P[3];
                            #pragma unroll
                            for (int q = 0; q < 4; ++q) {
                                const unsigned* u = (const unsigned*)&qq[q];
                                #pragma unroll
                                for (int d = 0; d < 4; ++d) {
                                    const int slot = q*8 + d*2;
                                    if (slot >= 28) break;
                                    float lo, hi; bf2(u[d], lo, hi);
                                    ROUTE(slot, lo * w);
                                    if (slot + 1 < 28) ROUTE(slot + 1, hi * w);
                                }
                            }
                        }
                    }

                    sv = fmaxf(sv, 0.f);
                    alpha = 1.f - __expf(-sv * dist);
                    cr = __fdividef(1.f, 1.f + __expf(-a0));
                    cg = __fdividef(1.f, 1.f + __expf(-a1));
                    cb = __fdividef(1.f, 1.f + __expf(-a2));
                }

                float m = (s <= my_hi) ? (1.f - alpha + 1e-10f) : 1.f;
                float incl = m;
                #pragma unroll
                for (int off = 1; off < 64; off <<= 1) {
                    float nb = __shfl_up(incl, off);
                    if (lane >= off) incl *= nb;
                }
                float excl = __shfl_up(incl, 1);
                if (lane == 0) excl = 1.f;

                const float T = carry * excl;
                const float w = T * alpha;
                accR = fmaf(w, cr, accR);
                accG = fmaf(w, cg, accG);
                accB = fmaf(w, cb, accB);
                accL += w;
                carry *= __shfl(incl, 63);
            }
        }

        #pragma unroll
        for (int off = 32; off; off >>= 1) {
            accR += __shfl_xor(accR, off);
            accG += __shfl_xor(accG, off);
            accB += __shfl_xor(accB, off);
            accL += __shfl_xor(accL, off);
        }
        if (lane == 0) { sP[wave]=carry; sR[wave]=accR; sG[wave]=accG; sB[wave]=accB; sL[wave]=accL; }
        __syncthreads();
        if (tid == 0) {
            float T = 1.f, R = 0.f, G = 0.f, Bc = 0.f, L = 0.f;
            #pragma unroll
            for (int w = 0; w < 2; ++w) {
                R += T*sR[w]; G += T*sG[w]; Bc += T*sB[w]; L += T*sL[w]; T *= sP[w];
            }
            const float bg = 1.f - L;
            out[ray*3+0] = R + bg; out[ray*3+1] = G + bg; out[ray*3+2] = Bc + bg;
        }
        __syncthreads();
    }
}

// ====================== f32-direct render, 2 waves/ray, grouped loads ======================
__global__ __launch_bounds__(128)
void diag_render_f32(const float* __restrict__ rays_o,
                     const float* __restrict__ rays_d,
                     const float* __restrict__ sig,
                     const float* __restrict__ rgb,
                     float* __restrict__ out,
                     const float* __restrict__ zf, int reps)
{
    const int ray  = blockIdx.x;
    const int tid  = threadIdx.x;
    const int wave = tid >> 6;
    const int lane = tid & 63;

    const float ox = rays_o[ray*3+0], oy = rays_o[ray*3+1], oz = rays_o[ray*3+2];
    const float dxr = rays_d[ray*3+0], dyr = rays_d[ray*3+1], dzr = rays_d[ray*3+2];
    const float h = 2.6f * 1.7320508075688772f / 480.0f;

    const float dsq  = dxr*dxr + dyr*dyr + dzr*dzr;
    const float dinv = rsqrtf(dsq);
    const float dn   = sqrtf(dsq);
    const float X = dxr * dinv, Y = dyr * dinv, Z = dzr * dinv;
    const float shv[9] = {
        0.28209479177387814f, -0.4886025119029199f * Y, 0.4886025119029199f * Z,
        -0.4886025119029199f * X, 1.0925484305920792f * X * Y, -1.0925484305920792f * Y * Z,
        0.31539156525252005f * (2.0f * Z * Z - X * X - Y * Y),
        -1.0925484305920792f * X * Z, 0.5462742152960396f * (X * X - Y * Y),
    };
    const float dist = h * dn;

    __shared__ float sP[2], sR[2], sG[2], sB[2], sL[2];

    for (int rep = 0; rep < reps; ++rep) {
        const float oxj = ox + zf[rep];

        const float ax = (1.3f - oxj) / dxr, bx = (-1.3f - oxj) / dxr;
        const float ay = (1.3f - oy) / dyr,  by = (-1.3f - oy) / dyr;
        const float az = (1.3f - oz) / dzr,  bz = (-1.3f - oz) / dzr;
        float start = fmaxf(fmaxf(fminf(ax, bx), fminf(ay, by)), fminf(az, bz));
        start = fminf(fmaxf(start, 0.2f), 6.0f);

        const float B = 1.3164f;
        const float mx1 = ( B - oxj) / dxr, mx0 = (-B - oxj) / dxr;
        const float my1 = ( B - oy) / dyr,  my0 = (-B - oy) / dyr;
        const float mz1 = ( B - oz) / dzr,  mz0 = (-B - oz) / dzr;
        float tl = fmaxf(fmaxf(fminf(mx0, mx1), fminf(my0, my1)), fminf(mz0, mz1));
        float th = fminf(fminf(fmaxf(mx0, mx1), fmaxf(my0, my1)), fmaxf(mz0, mz1));
        tl = fmaxf(tl, start);
        th = fminf(th, fmaf((float)NPTS, h, start));
        int s_lo, s_hi;
        if (th < tl) { s_lo = 0; s_hi = -1; }
        else {
            s_lo = max(0,    (int)floorf((tl - start) / h) - 1);
            s_hi = min(NPTS, (int)ceilf ((th - start) / h) + 1);
        }

        float accR = 0.f, accG = 0.f, accB = 0.f, accL = 0.f;
        float carry = 1.0f;

        const int nlive = s_hi - s_lo + 1;
        if (nlive > 0) {
            const int chunk = (nlive + 1) >> 1;
            const int my_lo = s_lo + wave * chunk;
            const int my_hi = min(my_lo + chunk - 1, s_hi);

            for (int basei = my_lo; basei <= my_hi; basei += 64) {
                const int s = basei + lane;
                float alpha = 0.f, cr = 0.f, cg = 0.f, cb = 0.f;
                if (s <= my_hi) {
                    const float t  = fmaf((float)s, h, start);
                    const float px = fmaf(dxr, t, oxj);
                    const float py = fmaf(dyr, t, oy);
                    const float pz = fmaf(dzr, t, oz);
                    const float fx = fmaf(px, 61.153846153846f, 79.5f);
                    const float fy = fmaf(py, 61.153846153846f, 79.5f);
                    const float fz = fmaf(pz, 61.153846153846f, 79.5f);
                    const float fxf = floorf(fx), fyf = floorf(fy), fzf = floorf(fz);
                    const int   x0 = (int)fxf, y0 = (int)fyf, z0 = (int)fzf;
                    const float wx1 = fx - fxf, wy1 = fy - fyf, wz1 = fz - fzf;
                    const float wx0 = 1.f - wx1, wy0 = 1.f - wy1, wz0 = 1.f - wz1;

                    float sv = 0.f, a0 = 0.f, a1 = 0.f, a2 = 0.f;

                    if (x0 >= 0 && x0 <= 158 && y0 >= 0 && y0 <= 158 && z0 >= 0 && z0 <= 158) {
                        const float w00 = wz0*wy0, w01 = wz0*wy1, w10 = wz1*wy0, w11 = wz1*wy1;
                        const size_t bofs = (size_t)z0 * ZSTR + (size_t)y0 * YSTR + (size_t)x0;
                        // 28 channels (0 = sigma, 1..27 = rgb sh) in 4 groups of 7:
                        // batch 28 float2 gathers per group before consuming.
                        #pragma unroll
                        for (int g = 0; g < 4; ++g) {
                            f2_u r[7][4];
                            #pragma unroll
                            for (int c = 0; c < 7; ++c) {
                                const int ch = g*7 + c;
                                const float* bp = (ch == 0 ? sig + bofs
                                                           : rgb + (size_t)(ch-1)*VOX + bofs);
                                r[c][0] = *(const f2_u*)(bp);
                                r[c][1] = *(const f2_u*)(bp + YSTR);
                                r[c][2] = *(const f2_u*)(bp + ZSTR);
                                r[c][3] = *(const f2_u*)(bp + ZSTR + YSTR);
                            }
                            #pragma unroll
                            for (int c = 0; c < 7; ++c) {
                                const int ch = g*7 + c;
                                const float v0 = fmaf(r[c][0].y, wx1, r[c][0].x * wx0);
                                const float v1 = fmaf(r[c][1].y, wx1, r[c][1].x * wx0);
                                const float v2 = fmaf(r[c][2].y, wx1, r[c][2].x * wx0);
                                const float v3 = fmaf(r[c][3].y, wx1, r[c][3].x * wx0);
                                const float v  = fmaf(v3, w11, fmaf(v2, w10, fmaf(v1, w01, v0 * w00)));
                                if (ch == 0) sv = v;
                                else {
                                    const int j = ch - 1;
                                    const float ccoef = shv[j % 9] * v;
                                    if (j < 9) a0 += ccoef;
                                    else if (j < 18) a1 += ccoef;
                                    else a2 += ccoef;
                                }
                            }
                        }
                    } else {
                        const float vwx0 = (x0   >= 0 && x0   < RESN) ? wx0 : 0.f;
                        const float vwx1 = (x0+1 >= 0 && x0+1 < RESN) ? wx1 : 0.f;
                        const float vwy0 = (y0   >= 0 && y0   < RESN) ? wy0 : 0.f;
                        const float vwy1 = (y0+1 >= 0 && y0+1 < RESN) ? wy1 : 0.f;
                        const float vwz0 = (z0   >= 0 && z0   < RESN) ? wz0 : 0.f;
                        const float vwz1 = (z0+1 >= 0 && z0+1 < RESN) ? wz1 : 0.f;
                        const int cx0 = min(max(x0,   0), RESN-1), cx1 = min(max(x0+1, 0), RESN-1);
                        const int cy0 = min(max(y0,   0), RESN-1), cy1 = min(max(y0+1, 0), RESN-1);
                        const int cz0 = min(max(z0,   0), RESN-1), cz1 = min(max(z0+1, 0), RESN-1);
                        const float cw[8] = { vwz0*vwy0*vwx0, vwz0*vwy0*vwx1,
                                              vwz0*vwy1*vwx0, vwz0*vwy1*vwx1,
                                              vwz1*vwy0*vwx0, vwz1*vwy0*vwx1,
                                              vwz1*vwy1*vwx0, vwz1*vwy1*vwx1 };
                        const size_t co[8] = {
                            (size_t)cz0*ZSTR + (size_t)cy0*YSTR + cx0,
                            (size_t)cz0*ZSTR + (size_t)cy0*YSTR + cx1,
                            (size_t)cz0*ZSTR + (size_t)cy1*YSTR + cx0,
                            (size_t)cz0*ZSTR + (size_t)cy1*YSTR + cx1,
                            (size_t)cz1*ZSTR + (size_t)cy0*YSTR + cx0,
                            (size_t)cz1*ZSTR + (size_t)cy0*YSTR + cx1,
                            (size_t)cz1*ZSTR + (size_t)cy1*YSTR + cx0,
                            (size_t)cz1*ZSTR + (size_t)cy1*YSTR + cx1 };
                        #pragma unroll
                        for (int j8 = 0; j8 < 8; ++j8) {
                            if (cw[j8] != 0.f) {
                                const float wj = cw[j8];
                                sv = fmaf(sig[co[j8]], wj, sv);
                                const float* rp = rgb + co[j8];
                                float t0 = 0.f, t1 = 0.f, t2 = 0.f;
                                #pragma unroll
                                for (int k = 0; k < 9; ++k) {
                                    t0 = fmaf(rp[(size_t)(k     )*VOX], shv[k], t0);
                                    t1 = fmaf(rp[(size_t)(k +  9)*VOX], shv[k], t1);
                                    t2 = fmaf(rp[(size_t)(k + 18)*VOX], shv[k], t2);
                                }
                                a0 = fmaf(t0, wj, a0);
                                a1 = fmaf(t1, wj, a1);
                                a2 = fmaf(t2, wj, a2);
                            }
                        }
                    }

                    sv = fmaxf(sv, 0.f);
                    alpha = 1.f - __expf(-sv * dist);
                    cr = __fdividef(1.f, 1.f + __expf(-a0));
                    cg = __fdividef(1.f, 1.f + __expf(-a1));
                    cb = __fdividef(1.f, 1.f + __expf(-a2));
                }

                float m = (s <= my_hi) ? (1.f - alpha + 1e-10f) : 1.f;
                float incl = m;
                #pragma unroll
                for (int off = 1; off < 64; off <<= 1) {
                    float nb = __shfl_up(incl, off);
                    if (lane >= off) incl *= nb;
                }
                float excl = __shfl_up(incl, 1);
                if (lane == 0) excl = 1.f;

                const float T = carry * excl;
                const float w = T * alpha;
                accR = fmaf(w, cr, accR);
                accG = fmaf(w, cg, accG);
                accB = fmaf(w, cb, accB);
                accL += w;
                carry *= __shfl(incl, 63);
            }
        }

        #pragma unroll
        for (int off = 32; off; off >>= 1) {
            accR += __shfl_xor(accR, off);
            accG += __shfl_xor(accG, off);
            accB += __shfl_xor(accB, off);
            accL += __shfl_xor(accL, off);
        }
        if (lane == 0) { sP[wave]=carry; sR[wave]=accR; sG[wave]=accG; sB[wave]=accB; sL[wave]=accL; }
        __syncthreads();
        if (tid == 0) {
            float T = 1.f, R = 0.f, G = 0.f, Bc = 0.f, L = 0.f;
            #pragma unroll
            for (int w = 0; w < 2; ++w) {
                R += T*sR[w]; G += T*sG[w]; Bc += T*sB[w]; L += T*sL[w]; T *= sP[w];
            }
            const float bg = 1.f - L;
            out[ray*3+0] = R + bg; out[ray*3+1] = G + bg; out[ray*3+2] = Bc + bg;
        }
        __syncthreads();
    }
}

extern "C" void kernel_launch(void* const* d_in, const int* in_sizes, int n_in,
                              void* d_out, int out_size, void* d_ws, size_t ws_size,
                              hipStream_t stream) {
    const float* rays_o = (const float*)d_in[0];
    const float* rays_d = (const float*)d_in[1];
    const float* sig    = (const float*)d_in[2];
    const float* rgb    = (const float*)d_in[3];
    float* out = (float*)d_out;

    // zero scratch header: zf/zi runtime-zero jitters (defeats LICM of rep loops)
    hipMemsetAsync(d_ws, 0, 1024, stream);
    const float* zf = (const float*)d_ws;
    const int*   zi = (const int*)d_ws;

    const size_t need = 1024 + (size_t)VOX * REC * sizeof(unsigned short);
    if (ws_size >= need) {
        unsigned short* rec = (unsigned short*)((char*)d_ws + 1024);
        // Diagnostic round: repeat each kernel so all three rise above the
        // ~270us fillBuffer dispatches and appear in rocprof top-5 w/ counters.
        diag_transpose <<<VOX / 256, 256, 0, stream>>>(sig, rgb, rec, zi, 2);
        diag_render_rec<<<NRAYS, 128, 0, stream>>>(rays_o, rays_d, rec, out, zf, 3);
        diag_render_f32<<<NRAYS, 128, 0, stream>>>(rays_o, rays_d, sig, rgb, out, zf, 4);
    } else {
        diag_render_f32<<<NRAYS, 128, 0, stream>>>(rays_o, rays_d, sig, rgb, out, zf, 1);
    }
}

// Round 9
// 658.192 us; speedup vs baseline: 2.2979x; 2.2979x over previous
//
#include <hip/hip_runtime.h>
#include <math.h>

#define RESN   160
#define VOX    4096000          // 160^3
#define YSTR   160
#define ZSTR   25600            // 160*160
#define SCOUNT 479              // samples per ray (s = 0..478)
#define NPTS   478              // last sample index
#define NRAYS  2048

typedef float f2_u __attribute__((ext_vector_type(2), aligned(4)));

// ======================= phase 1: per-sample, perfectly balanced =======================
__global__ __launch_bounds__(256)
void p1_samples(const float* __restrict__ rays_o,
                const float* __restrict__ rays_d,
                const float* __restrict__ sig,
                const float* __restrict__ rgb,
                float4* __restrict__ sc)
{
    const int gid = blockIdx.x * 256 + threadIdx.x;     // 0 .. NRAYS*SCOUNT-1
    const int ray = gid / SCOUNT;
    const int s   = gid - ray * SCOUNT;

    const float ox = rays_o[ray*3+0], oy = rays_o[ray*3+1], oz = rays_o[ray*3+2];
    const float dxr = rays_d[ray*3+0], dyr = rays_d[ray*3+1], dzr = rays_d[ray*3+2];
    const float h = 2.6f * 1.7320508075688772f / 480.0f;

    // start t (reference semantics)
    const float ax = (1.3f - ox) / dxr, bx = (-1.3f - ox) / dxr;
    const float ay = (1.3f - oy) / dyr, by = (-1.3f - oy) / dyr;
    const float az = (1.3f - oz) / dzr, bz = (-1.3f - oz) / dzr;
    float start = fmaxf(fmaxf(fminf(ax, bx), fminf(ay, by)), fminf(az, bz));
    start = fminf(fmaxf(start, 0.2f), 6.0f);

    // live range (1-voxel margin)
    const float B = 1.3164f;
    const float mx1 = ( B - ox) / dxr, mx0 = (-B - ox) / dxr;
    const float my1 = ( B - oy) / dyr, my0 = (-B - oy) / dyr;
    const float mz1 = ( B - oz) / dzr, mz0 = (-B - oz) / dzr;
    float tl = fmaxf(fmaxf(fminf(mx0, mx1), fminf(my0, my1)), fminf(mz0, mz1));
    float th = fminf(fminf(fmaxf(mx0, mx1), fmaxf(my0, my1)), fmaxf(mz0, mz1));
    tl = fmaxf(tl, start);
    th = fminf(th, fmaf((float)NPTS, h, start));
    int s_lo = 0, s_hi = -1;
    if (th >= tl) {
        s_lo = max(0,    (int)floorf((tl - start) / h) - 1);
        s_hi = min(NPTS, (int)ceilf ((th - start) / h) + 1);
    }

    if (s < s_lo || s > s_hi) {                 // dead sample: exact zeros
        sc[gid] = make_float4(0.f, 0.f, 0.f, 0.f);
        return;
    }

    // SH of normalized dir
    const float dsq  = dxr*dxr + dyr*dyr + dzr*dzr;
    const float dinv = rsqrtf(dsq);
    const float dn   = sqrtf(dsq);
    const float X = dxr * dinv, Y = dyr * dinv, Z = dzr * dinv;
    const float shv[9] = {
        0.28209479177387814f, -0.4886025119029199f * Y, 0.4886025119029199f * Z,
        -0.4886025119029199f * X, 1.0925484305920792f * X * Y, -1.0925484305920792f * Y * Z,
        0.31539156525252005f * (2.0f * Z * Z - X * X - Y * Y),
        -1.0925484305920792f * X * Z, 0.5462742152960396f * (X * X - Y * Y),
    };
    const float dist = h * dn;

    const float t  = fmaf((float)s, h, start);
    const float px = fmaf(dxr, t, ox);
    const float py = fmaf(dyr, t, oy);
    const float pz = fmaf(dzr, t, oz);
    const float fx = fmaf(px, 61.153846153846f, 79.5f);
    const float fy = fmaf(py, 61.153846153846f, 79.5f);
    const float fz = fmaf(pz, 61.153846153846f, 79.5f);
    const float fxf = floorf(fx), fyf = floorf(fy), fzf = floorf(fz);
    const int   x0 = (int)fxf, y0 = (int)fyf, z0 = (int)fzf;
    const float wx1 = fx - fxf, wy1 = fy - fyf, wz1 = fz - fzf;
    const float wx0 = 1.f - wx1, wy0 = 1.f - wy1, wz0 = 1.f - wz1;

    float sv = 0.f, a0 = 0.f, a1 = 0.f, a2 = 0.f;

    if (x0 >= 0 && x0 <= 158 && y0 >= 0 && y0 <= 158 && z0 >= 0 && z0 <= 158) {
        const float w00 = wz0*wy0, w01 = wz0*wy1, w10 = wz1*wy0, w11 = wz1*wy1;
        const size_t bofs = (size_t)z0 * ZSTR + (size_t)y0 * YSTR + (size_t)x0;
        // 28 channels in 4 groups of 7; batch 28 float2 gathers per group
        #pragma unroll
        for (int g = 0; g < 4; ++g) {
            f2_u r[7][4];
            #pragma unroll
            for (int c = 0; c < 7; ++c) {
                const int ch = g*7 + c;
                const float* bp = (ch == 0 ? sig + bofs
                                           : rgb + (size_t)(ch-1)*VOX + bofs);
                r[c][0] = *(const f2_u*)(bp);
                r[c][1] = *(const f2_u*)(bp + YSTR);
                r[c][2] = *(const f2_u*)(bp + ZSTR);
                r[c][3] = *(const f2_u*)(bp + ZSTR + YSTR);
            }
            #pragma unroll
            for (int c = 0; c < 7; ++c) {
                const int ch = g*7 + c;
                const float v0 = fmaf(r[c][0].y, wx1, r[c][0].x * wx0);
                const float v1 = fmaf(r[c][1].y, wx1, r[c][1].x * wx0);
                const float v2 = fmaf(r[c][2].y, wx1, r[c][2].x * wx0);
                const float v3 = fmaf(r[c][3].y, wx1, r[c][3].x * wx0);
                const float v  = fmaf(v3, w11, fmaf(v2, w10, fmaf(v1, w01, v0 * w00)));
                if (ch == 0) sv = v;
                else {
                    const int j = ch - 1;
                    const float ccoef = shv[j % 9] * v;
                    if (j < 9) a0 += ccoef;
                    else if (j < 18) a1 += ccoef;
                    else a2 += ccoef;
                }
            }
        }
    } else {
        // boundary: masked per-corner (rare)
        const float vwx0 = (x0   >= 0 && x0   < RESN) ? wx0 : 0.f;
        const float vwx1 = (x0+1 >= 0 && x0+1 < RESN) ? wx1 : 0.f;
        const float vwy0 = (y0   >= 0 && y0   < RESN) ? wy0 : 0.f;
        const float vwy1 = (y0+1 >= 0 && y0+1 < RESN) ? wy1 : 0.f;
        const float vwz0 = (z0   >= 0 && z0   < RESN) ? wz0 : 0.f;
        const float vwz1 = (z0+1 >= 0 && z0+1 < RESN) ? wz1 : 0.f;
        const int cx0 = min(max(x0,   0), RESN-1), cx1 = min(max(x0+1, 0), RESN-1);
        const int cy0 = min(max(y0,   0), RESN-1), cy1 = min(max(y0+1, 0), RESN-1);
        const int cz0 = min(max(z0,   0), RESN-1), cz1 = min(max(z0+1, 0), RESN-1);
        const float cw[8] = { vwz0*vwy0*vwx0, vwz0*vwy0*vwx1,
                              vwz0*vwy1*vwx0, vwz0*vwy1*vwx1,
                              vwz1*vwy0*vwx0, vwz1*vwy0*vwx1,
                              vwz1*vwy1*vwx0, vwz1*vwy1*vwx1 };
        const size_t co[8] = {
            (size_t)cz0*ZSTR + (size_t)cy0*YSTR + cx0,
            (size_t)cz0*ZSTR + (size_t)cy0*YSTR + cx1,
            (size_t)cz0*ZSTR + (size_t)cy1*YSTR + cx0,
            (size_t)cz0*ZSTR + (size_t)cy1*YSTR + cx1,
            (size_t)cz1*ZSTR + (size_t)cy0*YSTR + cx0,
            (size_t)cz1*ZSTR + (size_t)cy0*YSTR + cx1,
            (size_t)cz1*ZSTR + (size_t)cy1*YSTR + cx0,
            (size_t)cz1*ZSTR + (size_t)cy1*YSTR + cx1 };
        #pragma unroll
        for (int j8 = 0; j8 < 8; ++j8) {
            if (cw[j8] != 0.f) {
                const float wj = cw[j8];
                sv = fmaf(sig[co[j8]], wj, sv);
                const float* rp = rgb + co[j8];
                float t0 = 0.f, t1 = 0.f, t2 = 0.f;
                #pragma unroll
                for (int k = 0; k < 9; ++k) {
                    t0 = fmaf(rp[(size_t)(k     )*VOX], shv[k], t0);
                    t1 = fmaf(rp[(size_t)(k +  9)*VOX], shv[k], t1);
                    t2 = fmaf(rp[(size_t)(k + 18)*VOX], shv[k], t2);
                }
                a0 = fmaf(t0, wj, a0);
                a1 = fmaf(t1, wj, a1);
                a2 = fmaf(t2, wj, a2);
            }
        }
    }

    sv = fmaxf(sv, 0.f);
    const float alpha = 1.f - __expf(-sv * dist);
    const float cr = __fdividef(1.f, 1.f + __expf(-a0));
    const float cg = __fdividef(1.f, 1.f + __expf(-a1));
    const float cb = __fdividef(1.f, 1.f + __expf(-a2));
    sc[gid] = make_float4(alpha, cr, cg, cb);
}

// ======================= phase 2: per-ray scan (exact reference cumprod) ==============
__global__ __launch_bounds__(64)
void p2_scan(const float4* __restrict__ sc, float* __restrict__ out)
{
    const int ray  = blockIdx.x;
    const int lane = threadIdx.x;

    float accR = 0.f, accG = 0.f, accB = 0.f, accL = 0.f;
    float carry = 1.0f;
    const float4* base = sc + (size_t)ray * SCOUNT;

    for (int basei = 0; basei < SCOUNT; basei += 64) {
        const int s = basei + lane;
        float alpha = 0.f, cr = 0.f, cg = 0.f, cb = 0.f;
        bool live = (s < SCOUNT);
        if (live) {
            const float4 v = base[s];
            alpha = v.x; cr = v.y; cg = v.z; cb = v.w;
        }
        // reference includes the +1e-10 on EVERY sample (even alpha==0)
        float m = live ? (1.f - alpha + 1e-10f) : 1.f;
        float incl = m;
        #pragma unroll
        for (int off = 1; off < 64; off <<= 1) {
            float nb = __shfl_up(incl, off);
            if (lane >= off) incl *= nb;
        }
        float excl = __shfl_up(incl, 1);
        if (lane == 0) excl = 1.f;

        const float T = carry * excl;
        const float w = T * alpha;
        accR = fmaf(w, cr, accR);
        accG = fmaf(w, cg, accG);
        accB = fmaf(w, cb, accB);
        accL += w;
        carry *= __shfl(incl, 63);
    }

    #pragma unroll
    for (int off = 32; off; off >>= 1) {
        accR += __shfl_xor(accR, off);
        accG += __shfl_xor(accG, off);
        accB += __shfl_xor(accB, off);
        accL += __shfl_xor(accL, off);
    }
    if (lane == 0) {
        const float bg = 1.f - accL;
        out[ray*3+0] = accR + bg;
        out[ray*3+1] = accG + bg;
        out[ray*3+2] = accB + bg;
    }
}

// ======================= fallback: fused single-kernel f32 (ws too small) =============
__global__ __launch_bounds__(128)
void render_f32_fused(const float* __restrict__ rays_o,
                      const float* __restrict__ rays_d,
                      const float* __restrict__ sig,
                      const float* __restrict__ rgb,
                      float* __restrict__ out)
{
    const int ray  = blockIdx.x;
    const int tid  = threadIdx.x;
    const int wave = tid >> 6;
    const int lane = tid & 63;

    const float ox = rays_o[ray*3+0], oy = rays_o[ray*3+1], oz = rays_o[ray*3+2];
    const float dxr = rays_d[ray*3+0], dyr = rays_d[ray*3+1], dzr = rays_d[ray*3+2];
    const float h = 2.6f * 1.7320508075688772f / 480.0f;

    const float ax = (1.3f - ox) / dxr, bx = (-1.3f - ox) / dxr;
    const float ay = (1.3f - oy) / dyr, by = (-1.3f - oy) / dyr;
    const float az = (1.3f - oz) / dzr, bz = (-1.3f - oz) / dzr;
    float start = fmaxf(fmaxf(fminf(ax, bx), fminf(ay, by)), fminf(az, bz));
    start = fminf(fmaxf(start, 0.2f), 6.0f);

    const float B = 1.3164f;
    const float mx1 = ( B - ox) / dxr, mx0 = (-B - ox) / dxr;
    const float my1 = ( B - oy) / dyr, my0 = (-B - oy) / dyr;
    const float mz1 = ( B - oz) / dzr, mz0 = (-B - oz) / dzr;
    float tl = fmaxf(fmaxf(fminf(mx0, mx1), fminf(my0, my1)), fminf(mz0, mz1));
    float th = fminf(fminf(fmaxf(mx0, mx1), fmaxf(my0, my1)), fmaxf(mz0, mz1));
    tl = fmaxf(tl, start);
    th = fminf(th, fmaf((float)NPTS, h, start));
    int s_lo = 0, s_hi = -1;
    if (th >= tl) {
        s_lo = max(0,    (int)floorf((tl - start) / h) - 1);
        s_hi = min(NPTS, (int)ceilf ((th - start) / h) + 1);
    }

    const float dsq  = dxr*dxr + dyr*dyr + dzr*dzr;
    const float dinv = rsqrtf(dsq);
    const float dn   = sqrtf(dsq);
    const float X = dxr * dinv, Y = dyr * dinv, Z = dzr * dinv;
    const float shv[9] = {
        0.28209479177387814f, -0.4886025119029199f * Y, 0.4886025119029199f * Z,
        -0.4886025119029199f * X, 1.0925484305920792f * X * Y, -1.0925484305920792f * Y * Z,
        0.31539156525252005f * (2.0f * Z * Z - X * X - Y * Y),
        -1.0925484305920792f * X * Z, 0.5462742152960396f * (X * X - Y * Y),
    };
    const float dist = h * dn;

    float accR = 0.f, accG = 0.f, accB = 0.f, accL = 0.f;
    float carry = 1.0f;

    const int nlive = s_hi - s_lo + 1;
    if (nlive > 0) {
        const int chunk = (nlive + 1) >> 1;
        const int my_lo = s_lo + wave * chunk;
        const int my_hi = min(my_lo + chunk - 1, s_hi);

        for (int basei = my_lo; basei <= my_hi; basei += 64) {
            const int s = basei + lane;
            float alpha = 0.f, cr = 0.f, cg = 0.f, cb = 0.f;
            if (s <= my_hi) {
                const float t  = fmaf((float)s, h, start);
                const float px = fmaf(dxr, t, ox);
                const float py = fmaf(dyr, t, oy);
                const float pz = fmaf(dzr, t, oz);
                const float fx = fmaf(px, 61.153846153846f, 79.5f);
                const float fy = fmaf(py, 61.153846153846f, 79.5f);
                const float fz = fmaf(pz, 61.153846153846f, 79.5f);
                const float fxf = floorf(fx), fyf = floorf(fy), fzf = floorf(fz);
                const int   x0 = (int)fxf, y0 = (int)fyf, z0 = (int)fzf;
                const float wx1 = fx - fxf, wy1 = fy - fyf, wz1 = fz - fzf;
                const float wx0 = 1.f - wx1, wy0 = 1.f - wy1, wz0 = 1.f - wz1;
                float sv = 0.f, a0 = 0.f, a1 = 0.f, a2 = 0.f;
                if (x0 >= 0 && x0 <= 158 && y0 >= 0 && y0 <= 158 && z0 >= 0 && z0 <= 158) {
                    const float w00 = wz0*wy0, w01 = wz0*wy1, w10 = wz1*wy0, w11 = wz1*wy1;
                    const size_t bofs = (size_t)z0 * ZSTR + (size_t)y0 * YSTR + (size_t)x0;
                    #pragma unroll
                    for (int g = 0; g < 4; ++g) {
                        f2_u r[7][4];
                        #pragma unroll
                        for (int c = 0; c < 7; ++c) {
                            const int ch = g*7 + c;
                            const float* bp = (ch == 0 ? sig + bofs
                                                       : rgb + (size_t)(ch-1)*VOX + bofs);
                            r[c][0] = *(const f2_u*)(bp);
                            r[c][1] = *(const f2_u*)(bp + YSTR);
                            r[c][2] = *(const f2_u*)(bp + ZSTR);
                            r[c][3] = *(const f2_u*)(bp + ZSTR + YSTR);
                        }
                        #pragma unroll
                        for (int c = 0; c < 7; ++c) {
                            const int ch = g*7 + c;
                            const float v0 = fmaf(r[c][0].y, wx1, r[c][0].x * wx0);
                            const float v1 = fmaf(r[c][1].y, wx1, r[c][1].x * wx0);
                            const float v2 = fmaf(r[c][2].y, wx1, r[c][2].x * wx0);
                            const float v3 = fmaf(r[c][3].y, wx1, r[c][3].x * wx0);
                            const float v  = fmaf(v3, w11, fmaf(v2, w10, fmaf(v1, w01, v0 * w00)));
                            if (ch == 0) sv = v;
                            else {
                                const int j = ch - 1;
                                const float ccoef = shv[j % 9] * v;
                                if (j < 9) a0 += ccoef;
                                else if (j < 18) a1 += ccoef;
                                else a2 += ccoef;
                            }
                        }
                    }
                } else {
                    const float vwx0 = (x0   >= 0 && x0   < RESN) ? wx0 : 0.f;
                    const float vwx1 = (x0+1 >= 0 && x0+1 < RESN) ? wx1 : 0.f;
                    const float vwy0 = (y0   >= 0 && y0   < RESN) ? wy0 : 0.f;
                    const float vwy1 = (y0+1 >= 0 && y0+1 < RESN) ? wy1 : 0.f;
                    const float vwz0 = (z0   >= 0 && z0   < RESN) ? wz0 : 0.f;
                    const float vwz1 = (z0+1 >= 0 && z0+1 < RESN) ? wz1 : 0.f;
                    const int cx0 = min(max(x0,   0), RESN-1), cx1 = min(max(x0+1, 0), RESN-1);
                    const int cy0 = min(max(y0,   0), RESN-1), cy1 = min(max(y0+1, 0), RESN-1);
                    const int cz0 = min(max(z0,   0), RESN-1), cz1 = min(max(z0+1, 0), RESN-1);
                    const float cw[8] = { vwz0*vwy0*vwx0, vwz0*vwy0*vwx1,
                                          vwz0*vwy1*vwx0, vwz0*vwy1*vwx1,
                                          vwz1*vwy0*vwx0, vwz1*vwy0*vwx1,
                                          vwz1*vwy1*vwx0, vwz1*vwy1*vwx1 };
                    const size_t co[8] = {
                        (size_t)cz0*ZSTR + (size_t)cy0*YSTR + cx0,
                        (size_t)cz0*ZSTR + (size_t)cy0*YSTR + cx1,
                        (size_t)cz0*ZSTR + (size_t)cy1*YSTR + cx0,
                        (size_t)cz0*ZSTR + (size_t)cy1*YSTR + cx1,
                        (size_t)cz1*ZSTR + (size_t)cy0*YSTR + cx0,
                        (size_t)cz1*ZSTR + (size_t)cy0*YSTR + cx1,
                        (size_t)cz1*ZSTR + (size_t)cy1*YSTR + cx0,
                        (size_t)cz1*ZSTR + (size_t)cy1*YSTR + cx1 };
                    #pragma unroll
                    for (int j8 = 0; j8 < 8; ++j8) {
                        if (cw[j8] != 0.f) {
                            const float wj = cw[j8];
                            sv = fmaf(sig[co[j8]], wj, sv);
                            const float* rp = rgb + co[j8];
                            float t0 = 0.f, t1 = 0.f, t2 = 0.f;
                            #pragma unroll
                            for (int k = 0; k < 9; ++k) {
                                t0 = fmaf(rp[(size_t)(k     )*VOX], shv[k], t0);
                                t1 = fmaf(rp[(size_t)(k +  9)*VOX], shv[k], t1);
                                t2 = fmaf(rp[(size_t)(k + 18)*VOX], shv[k], t2);
                            }
                            a0 = fmaf(t0, wj, a0);
                            a1 = fmaf(t1, wj, a1);
                            a2 = fmaf(t2, wj, a2);
                        }
                    }
                }
                sv = fmaxf(sv, 0.f);
                alpha = 1.f - __expf(-sv * dist);
                cr = __fdividef(1.f, 1.f + __expf(-a0));
                cg = __fdividef(1.f, 1.f + __expf(-a1));
                cb = __fdividef(1.f, 1.f + __expf(-a2));
            }
            float m = (s <= my_hi) ? (1.f - alpha + 1e-10f) : 1.f;
            float incl = m;
            #pragma unroll
            for (int off = 1; off < 64; off <<= 1) {
                float nb = __shfl_up(incl, off);
                if (lane >= off) incl *= nb;
            }
            float excl = __shfl_up(incl, 1);
            if (lane == 0) excl = 1.f;
            const float T = carry * excl;
            const float w = T * alpha;
            accR = fmaf(w, cr, accR);
            accG = fmaf(w, cg, accG);
            accB = fmaf(w, cb, accB);
            accL += w;
            carry *= __shfl(incl, 63);
        }
    }

    #pragma unroll
    for (int off = 32; off; off >>= 1) {
        accR += __shfl_xor(accR, off);
        accG += __shfl_xor(accG, off);
        accB += __shfl_xor(accB, off);
        accL += __shfl_xor(accL, off);
    }
    __shared__ float sP[2], sR[2], sG[2], sB[2], sL[2];
    if (lane == 0) { sP[wave]=carry; sR[wave]=accR; sG[wave]=accG; sB[wave]=accB; sL[wave]=accL; }
    __syncthreads();
    if (tid == 0) {
        float T = 1.f, R = 0.f, G = 0.f, Bc = 0.f, L = 0.f;
        #pragma unroll
        for (int w = 0; w < 2; ++w) {
            R += T*sR[w]; G += T*sG[w]; Bc += T*sB[w]; L += T*sL[w]; T *= sP[w];
        }
        const float bg = 1.f - L;
        out[ray*3+0] = R + bg; out[ray*3+1] = G + bg; out[ray*3+2] = Bc + bg;
    }
}

extern "C" void kernel_launch(void* const* d_in, const int* in_sizes, int n_in,
                              void* d_out, int out_size, void* d_ws, size_t ws_size,
                              hipStream_t stream) {
    const float* rays_o = (const float*)d_in[0];
    const float* rays_d = (const float*)d_in[1];
    const float* sig    = (const float*)d_in[2];
    const float* rgb    = (const float*)d_in[3];
    float* out = (float*)d_out;

    const size_t need = (size_t)NRAYS * SCOUNT * sizeof(float4);   // ~15.7 MB
    if (ws_size >= need) {
        float4* sc = (float4*)d_ws;
        const int total = NRAYS * SCOUNT;                          // 980,992
        p1_samples<<<(total + 255) / 256, 256, 0, stream>>>(rays_o, rays_d, sig, rgb, sc);
        p2_scan  <<<NRAYS, 64, 0, stream>>>(sc, out);
    } else {
        render_f32_fused<<<NRAYS, 128, 0, stream>>>(rays_o, rays_d, sig, rgb, out);
    }
}